// Round 3
// baseline (507.731 us; speedup 1.0000x reference)
//
#include <hip/hip_runtime.h>
#include <math.h>

#define NCLS 16
#define DIM  64

// ---------------- K1a: init counters + Gram buffer ----------------
__global__ void k_init(int* __restrict__ cnt, float* __restrict__ G) {
    int t = blockIdx.x * blockDim.x + threadIdx.x;
    if (t < NCLS) cnt[t] = 0;
    for (int i = t; i < NCLS * DIM * DIM; i += gridDim.x * blockDim.x) G[i] = 0.f;
}

// ---------------- K1b: class histogram (block-aggregated) ----------------
__global__ void k_hist(const int* __restrict__ label, int n, int* __restrict__ cnt) {
    __shared__ int h[NCLS];
    if (threadIdx.x < NCLS) h[threadIdx.x] = 0;
    __syncthreads();
    int stride = gridDim.x * blockDim.x;
    for (int i = blockIdx.x * blockDim.x + threadIdx.x; i < n; i += stride)
        atomicAdd(&h[label[i]], 1);
    __syncthreads();
    if (threadIdx.x < NCLS) atomicAdd(&cnt[threadIdx.x], h[threadIdx.x]);
}

// ---------------- K1c: tiny exclusive scan ----------------
__global__ void k_scan(const int* __restrict__ cnt, int* __restrict__ base,
                       int* __restrict__ cursor) {
    if (threadIdx.x == 0) {
        int s = 0;
        for (int c = 0; c < NCLS; c++) { base[c] = s; cursor[c] = s; s += cnt[c]; }
    }
}

// ---------------- K1d: scatter row indices into class buckets ----------------
__global__ void k_scatter(const int* __restrict__ label, int n,
                          int* __restrict__ cursor, int* __restrict__ idx) {
    __shared__ int h[NCLS];
    __shared__ int cur[NCLS];
    if (threadIdx.x < NCLS) h[threadIdx.x] = 0;
    __syncthreads();
    int stride = gridDim.x * blockDim.x;
    for (int i = blockIdx.x * blockDim.x + threadIdx.x; i < n; i += stride)
        atomicAdd(&h[label[i]], 1);
    __syncthreads();
    if (threadIdx.x < NCLS)
        cur[threadIdx.x] = atomicAdd(&cursor[threadIdx.x], h[threadIdx.x]);
    __syncthreads();
    for (int i = blockIdx.x * blockDim.x + threadIdx.x; i < n; i += stride) {
        int p = atomicAdd(&cur[label[i]], 1);
        idx[p] = i;
    }
}

// ---------------- K2: per-class Gram via register 8x8 tiles ----------------
// (unchanged from R2 — spill-free, __launch_bounds__(256,4), LDS block reduce)
__global__ __launch_bounds__(256, 4) void k_gram(const float* __restrict__ feat,
                                                 const int* __restrict__ idx,
                                                 const int* __restrict__ base,
                                                 const int* __restrict__ cnt,
                                                 float* __restrict__ G) {
    const int c    = blockIdx.x & (NCLS - 1);
    const int blk  = blockIdx.x >> 4;          // 0..63
    const int wave = threadIdx.x >> 6;         // 0..3
    const int lane = threadIdx.x & 63;
    const int gw   = blk * 4 + wave;           // 0..255
    const int r0   = (lane >> 3) << 3;
    const int c0   = (lane & 7) << 3;
    const int m    = cnt[c];
    const int b0   = base[c];
    const int STEP = 256 * 2;

    float acc[8][8];
#pragma unroll
    for (int j = 0; j < 8; j++)
#pragma unroll
        for (int k = 0; k < 8; k++) acc[j][k] = 0.f;

    int ii[2];
    const int p0 = gw * 2;
#pragma unroll
    for (int q = 0; q < 2; q++) ii[q] = (p0 + q < m) ? idx[b0 + p0 + q] : -1;

    for (int p = p0; p < m; p += STEP) {
        float4 xa[2][2], xb[2][2];
#pragma unroll
        for (int q = 0; q < 2; q++) {
            if (ii[q] >= 0) {
                const float* rp = feat + (size_t)ii[q] * DIM;
                xa[q][0] = *(const float4*)(rp + r0);
                xa[q][1] = *(const float4*)(rp + r0 + 4);
                xb[q][0] = *(const float4*)(rp + c0);
                xb[q][1] = *(const float4*)(rp + c0 + 4);
            } else {
                float4 z = make_float4(0.f, 0.f, 0.f, 0.f);
                xa[q][0] = z; xa[q][1] = z; xb[q][0] = z; xb[q][1] = z;
            }
        }
        const int pn = p + STEP;
#pragma unroll
        for (int q = 0; q < 2; q++) ii[q] = (pn + q < m) ? idx[b0 + pn + q] : -1;

#pragma unroll
        for (int q = 0; q < 2; q++) {
            float av[8] = {xa[q][0].x, xa[q][0].y, xa[q][0].z, xa[q][0].w,
                           xa[q][1].x, xa[q][1].y, xa[q][1].z, xa[q][1].w};
            float bv[8] = {xb[q][0].x, xb[q][0].y, xb[q][0].z, xb[q][0].w,
                           xb[q][1].x, xb[q][1].y, xb[q][1].z, xb[q][1].w};
#pragma unroll
            for (int j = 0; j < 8; j++)
#pragma unroll
                for (int k = 0; k < 8; k++)
                    acc[j][k] = fmaf(av[j], bv[k], acc[j][k]);
        }
    }

    __shared__ float tile[DIM * DIM];
    for (int w = 0; w < 4; w++) {
        if (wave == w) {
            float* t = tile + r0 * DIM + c0;
            if (w == 0) {
#pragma unroll
                for (int j = 0; j < 8; j++) {
                    *(float4*)(t + j * DIM)     = make_float4(acc[j][0], acc[j][1], acc[j][2], acc[j][3]);
                    *(float4*)(t + j * DIM + 4) = make_float4(acc[j][4], acc[j][5], acc[j][6], acc[j][7]);
                }
            } else {
#pragma unroll
                for (int j = 0; j < 8; j++) {
                    float4 u0 = *(float4*)(t + j * DIM);
                    float4 u1 = *(float4*)(t + j * DIM + 4);
                    u0.x += acc[j][0]; u0.y += acc[j][1]; u0.z += acc[j][2]; u0.w += acc[j][3];
                    u1.x += acc[j][4]; u1.y += acc[j][5]; u1.z += acc[j][6]; u1.w += acc[j][7];
                    *(float4*)(t + j * DIM)     = u0;
                    *(float4*)(t + j * DIM + 4) = u1;
                }
            }
        }
        __syncthreads();
    }
    float* g = G + c * DIM * DIM;
    for (int e = threadIdx.x; e < DIM * DIM; e += 256)
        atomicAdd(&g[e], tile[e]);
}

// ---------------- K3: top eigenvector per class (v2) ----------------
// One wave per class. Shift from trace moments (no power-iteration estimate),
// then 7 in-LDS squarings: C = (G - sigma I)^128 (even power -> PSD, ~rank-1).
// v0 = column of C with max diagonal (sign convention falls out for free),
// polished by 8 applies. Effective power exponent 128*9 ~ 1152, matching the
// proven-passing R1 config. Symmetry of all iterates lets the per-lane
// A[lane][k] read be the coalesced shA[k*64+lane] (2-way bank alias = free).
__global__ __launch_bounds__(64) void k_eig(const float* __restrict__ G,
                                            float* __restrict__ V) {
    const int c    = blockIdx.x;
    const int lane = threadIdx.x;
    __shared__ float shA[DIM * DIM];

    float row[DIM];
    {
        const float4* g4 = (const float4*)(G + c * DIM * DIM + lane * DIM);
#pragma unroll
        for (int j4 = 0; j4 < 16; j4++) {
            float4 t = g4[j4];
            row[4 * j4 + 0] = t.x; row[4 * j4 + 1] = t.y;
            row[4 * j4 + 2] = t.z; row[4 * j4 + 3] = t.w;
        }
    }

    // --- shift from trace moments: mu = tr(G)/64, var = tr(G^2)/64 - mu^2 ---
    float diag = G[c * DIM * DIM + lane * (DIM + 1)];
    float ss = 0.f;
#pragma unroll
    for (int j = 0; j < DIM; j++) ss = fmaf(row[j], row[j], ss);
    float sd_ = diag, s2_ = ss;
#pragma unroll
    for (int msk = 1; msk < 64; msk <<= 1) {
        sd_ += __shfl_xor(sd_, msk);
        s2_ += __shfl_xor(s2_, msk);
    }
    float mu    = sd_ * (1.f / 64.f);
    float var   = fmaxf(s2_ * (1.f / 64.f) - mu * mu, 0.f);
    float sdev  = sqrtf(var);
    float sigma = mu - 0.2f * sdev;   // MP edges ~ mu +/- 2*sd -> 0.45 placement

    // subtract shift on the diagonal (j==lane), compile-time j so no dyn index
#pragma unroll
    for (int j = 0; j < DIM; j++) row[j] -= (j == lane) ? sigma : 0.f;

    // --- 7 squarings: row <- row^2 (rescaled by max|elem| each time) ---
    for (int sq = 0; sq < 7; sq++) {
        __syncthreads();
        {
            float4* a4 = (float4*)shA + lane * 16;
#pragma unroll
            for (int j4 = 0; j4 < 16; j4++)
                a4[j4] = make_float4(row[4 * j4 + 0], row[4 * j4 + 1],
                                     row[4 * j4 + 2], row[4 * j4 + 3]);
        }
        __syncthreads();
        float h[DIM];
#pragma unroll
        for (int j = 0; j < DIM; j++) h[j] = 0.f;
        for (int k = 0; k < DIM; k++) {
            float f = shA[k * DIM + lane];             // = A[lane][k] (symmetry)
            const float4* ak = (const float4*)(shA + k * DIM);  // row k, broadcast
#pragma unroll
            for (int j4 = 0; j4 < 16; j4++) {
                float4 t = ak[j4];
                h[4 * j4 + 0] = fmaf(f, t.x, h[4 * j4 + 0]);
                h[4 * j4 + 1] = fmaf(f, t.y, h[4 * j4 + 1]);
                h[4 * j4 + 2] = fmaf(f, t.z, h[4 * j4 + 2]);
                h[4 * j4 + 3] = fmaf(f, t.w, h[4 * j4 + 3]);
            }
        }
        float mx = 0.f;
#pragma unroll
        for (int j = 0; j < DIM; j++) mx = fmaxf(mx, fabsf(h[j]));
#pragma unroll
        for (int msk = 1; msk < 64; msk <<= 1)
            mx = fmaxf(mx, __shfl_xor(mx, msk));
        float inv = (mx > 0.f) ? (1.0f / mx) : 1.0f;
#pragma unroll
        for (int j = 0; j < DIM; j++) row[j] = h[j] * inv;
    }

    // --- write C, pick v0 = column with max diagonal ---
    __syncthreads();
    {
        float4* a4 = (float4*)shA + lane * 16;
#pragma unroll
        for (int j4 = 0; j4 < 16; j4++)
            a4[j4] = make_float4(row[4 * j4 + 0], row[4 * j4 + 1],
                                 row[4 * j4 + 2], row[4 * j4 + 3]);
    }
    __syncthreads();
    float d = shA[lane * (DIM + 1)];
    float dmax = d;
#pragma unroll
    for (int msk = 1; msk < 64; msk <<= 1)
        dmax = fmaxf(dmax, __shfl_xor(dmax, msk));
    unsigned long long bal = __ballot(d == dmax);
    int jstar = __ffsll(bal) - 1;

    float v[DIM];
    {
        const float4* cj = (const float4*)(shA + jstar * DIM);  // row j* == col j*
#pragma unroll
        for (int j4 = 0; j4 < 16; j4++) {
            float4 t = cj[j4];
            v[4 * j4 + 0] = t.x; v[4 * j4 + 1] = t.y;
            v[4 * j4 + 2] = t.z; v[4 * j4 + 3] = t.w;
        }
    }
    float vd = shA[jstar * DIM + lane];

    // --- 8 polishing applies of C (no normalization needed: |C|<=1, growth<=64^8)
    for (int it = 0; it < 8; it++) {
        float y0 = 0, y1 = 0, y2 = 0, y3 = 0;
#pragma unroll
        for (int j = 0; j < DIM; j += 4) {
            y0 = fmaf(row[j + 0], v[j + 0], y0);
            y1 = fmaf(row[j + 1], v[j + 1], y1);
            y2 = fmaf(row[j + 2], v[j + 2], y2);
            y3 = fmaf(row[j + 3], v[j + 3], y3);
        }
        float y = (y0 + y1) + (y2 + y3);
        __syncthreads();
        shA[lane] = y;
        __syncthreads();
        const float4* s4 = (const float4*)shA;
#pragma unroll
        for (int j4 = 0; j4 < 16; j4++) {
            float4 t = s4[j4];
            v[4 * j4 + 0] = t.x; v[4 * j4 + 1] = t.y;
            v[4 * j4 + 2] = t.z; v[4 * j4 + 3] = t.w;
        }
        vd = y;
    }

    // --- normalize + sign convention (v replicated -> no reduction needed) ---
    float nn = 0.f;
#pragma unroll
    for (int j = 0; j < DIM; j++) nn = fmaf(v[j], v[j], nn);
    float inv = (nn > 1e-30f) ? rsqrtf(nn) : 1.0f;
    float bm = -1.f, bv = 0.f;
#pragma unroll
    for (int j = 0; j < DIM; j++) {
        float a = fabsf(v[j]);
        if (a > bm) { bm = a; bv = v[j]; }
    }
    float s = (bv < 0.f) ? -inv : inv;
    V[c * DIM + lane] = vd * s;
}

// ---------------- K4: given[i] = <feat_i, V[label_i]> ----------------
__global__ __launch_bounds__(256) void k_out(const float* __restrict__ feat,
                                             const int* __restrict__ label,
                                             const float* __restrict__ V,
                                             float* __restrict__ out, int n) {
    int i = blockIdx.x * blockDim.x + threadIdx.x;
    if (i >= n) return;
    const float4* rp = (const float4*)(feat + (size_t)i * DIM);
    const float4* vp = (const float4*)(V + label[i] * DIM);
    float s0 = 0, s1 = 0, s2 = 0, s3 = 0;
#pragma unroll
    for (int j = 0; j < 16; j++) {
        float4 a = rp[j], b = vp[j];
        s0 = fmaf(a.x, b.x, s0);
        s1 = fmaf(a.y, b.y, s1);
        s2 = fmaf(a.z, b.z, s2);
        s3 = fmaf(a.w, b.w, s3);
    }
    out[i] = (s0 + s1) + (s2 + s3);
}

extern "C" void kernel_launch(void* const* d_in, const int* in_sizes, int n_in,
                              void* d_out, int out_size, void* d_ws, size_t ws_size,
                              hipStream_t stream) {
    const float* feat  = (const float*)d_in[0];
    const int*   label = (const int*)d_in[1];
    const int    n     = in_sizes[1];
    float*       out   = (float*)d_out;

    int*   cnt    = (int*)d_ws;
    int*   base   = cnt + 16;
    int*   cursor = cnt + 32;
    float* G      = (float*)(cnt + 64);          // 16 * 4096 floats
    float* V      = G + NCLS * DIM * DIM;        // 16 * 64 floats
    int*   idx    = (int*)(V + NCLS * DIM);      // n ints

    k_init<<<64, 256, 0, stream>>>(cnt, G);
    k_hist<<<256, 256, 0, stream>>>(label, n, cnt);
    k_scan<<<1, 64, 0, stream>>>(cnt, base, cursor);
    k_scatter<<<256, 256, 0, stream>>>(label, n, cursor, idx);
    k_gram<<<NCLS * 64, 256, 0, stream>>>(feat, idx, base, cnt, G);
    k_eig<<<NCLS, 64, 0, stream>>>(G, V);
    k_out<<<(n + 255) / 256, 256, 0, stream>>>(feat, label, V, out, n);
}